// Round 9
// baseline (111.782 us; speedup 1.0000x reference)
//
#include <hip/hip_runtime.h>
#include <hip/hip_bf16.h>

#define HH 8
#define NN 2048
#define DD 64

typedef __attribute__((ext_vector_type(8))) short bf16x8;
typedef __attribute__((ext_vector_type(4))) float f32x4;
typedef __attribute__((ext_vector_type(8))) unsigned short u16x8;
typedef unsigned short ushort_t;

static __device__ __forceinline__ unsigned short f2bf(float x) {
    union { float f; unsigned u; } un; un.f = x;
    unsigned r = un.u + 0x7FFFu + ((un.u >> 16) & 1u);  // RNE
    return (unsigned short)(r >> 16);
}
static __device__ __forceinline__ float bf2f(unsigned short u) {
    union { unsigned u; float f; } un; un.u = ((unsigned)u) << 16;
    return un.f;
}

// ---------------- ws layout (bytes) ----------------
// All of Q/K/VT/R are stored as FRAGMENT-MAJOR 1KB tiles: a tile is 16 rows x 32 cols
// (bf16); byte slot l*16 holds row (l&15), cols 8*(l>>4)..+8 -- exactly the 16B one
// MFMA lane consumes.  In-loop loads are therefore base + l*16 (fully coalesced 1KB).
#define OFF_Q  0u          // [head][jtile 0..127][dh 0..1] 1KB tiles   (2MB)
#define OFF_K  2097152u    // same geometry                              (2MB)
#define OFF_VT 4194304u    // [head][j32 0..63][s 0..3] 1KB tiles        (2MB)
#define OFF_R  6291456u    // [rtile 0..255][dh 0..1] 1KB tiles          (512KB)
#define OFF_P  6815744u    // partials: [256 streams][2 tiles][8 subs][32][68] f32 (35.7MB)
#define WS_NEED 42467328u

// ---------------- pre-pass: f32 -> bf16 fragment tiles (4x coarsened) ----------------
// blocks: [0,576) handle FOUR Q/K/rpe 16x64 tiles each (tile ids 4b..4b+3 in [0,2304):
// [0,1024) Q, [1024,2048) K, [2048,2304) rpe); [576,832) V chunks (64x64 transpose).
__global__ void pre_kernel(const float* __restrict__ q, const float* __restrict__ k,
                           const float* __restrict__ r, const float* __restrict__ v,
                           ushort_t* __restrict__ ws) {
    __shared__ __align__(16) ushort_t T[64][72];
    const int tid = threadIdx.x;
    const int b = blockIdx.x;
    if (b < 576) {
        // ---- four 16x64 tiles -> eight 1KB fragment tiles
        char* dsts[4];
        const int rr = tid >> 4, dc = (tid & 15) << 2;
        #pragma unroll
        for (int p = 0; p < 4; ++p) {
            const int t = 4 * b + p;
            const float* srcrow;
            char* dst;
            int row = rr;
            if (t < 1024) {
                int head = t >> 7, tile = t & 127;
                srcrow = q + ((size_t)head * NN + (size_t)tile * 16) * DD;
                dst = (char*)ws + OFF_Q + (size_t)head * 262144 + (size_t)tile * 2048;
            } else if (t < 2048) {
                int tt = t - 1024; int head = tt >> 7, tile = tt & 127;
                srcrow = k + ((size_t)head * NN + (size_t)tile * 16) * DD;
                dst = (char*)ws + OFF_K + (size_t)head * 262144 + (size_t)tile * 2048;
            } else {
                int tile = t - 2048;
                dst = (char*)ws + OFF_R + (size_t)tile * 2048;
                int gr = tile * 16 + rr; if (gr > 4094) gr = 4094;   // bake the clamp
                srcrow = r + (size_t)gr * DD; row = 0;
            }
            float4 f = *(const float4*)&srcrow[(size_t)row * DD + dc];
            T[16 * p + rr][dc + 0] = f2bf(f.x); T[16 * p + rr][dc + 1] = f2bf(f.y);
            T[16 * p + rr][dc + 2] = f2bf(f.z); T[16 * p + rr][dc + 3] = f2bf(f.w);
            dsts[p] = dst;
        }
        __syncthreads();
        if (tid < 128) {
            const int dh = tid >> 6, l = tid & 63, lq = l >> 4, ln = l & 15;
            #pragma unroll
            for (int p = 0; p < 4; ++p) {
                u16x8 x = *(const u16x8*)&T[16 * p + ln][32 * dh + 8 * lq];
                *(u16x8*)(dsts[p] + dh * 1024 + l * 16) = x;
            }
        }
    } else {
        // ---- V chunk: 64 rows (j) x 64 cols (d) -> transpose -> 8 fragment tiles
        const int c = b - 576;
        const int h = c >> 5;
        const int n0 = (c & 31) * 64;
        const float* vh = v + (size_t)h * NN * DD;
        #pragma unroll
        for (int p = 0; p < 4; ++p) {
            int c2 = tid + 256 * p; int rr = c2 >> 4, dc = (c2 & 15) << 2;
            float4 f = *(const float4*)&vh[(size_t)(n0 + rr) * DD + dc];
            T[dc + 0][rr] = f2bf(f.x); T[dc + 1][rr] = f2bf(f.y);
            T[dc + 2][rr] = f2bf(f.z); T[dc + 3][rr] = f2bf(f.w);
        }
        __syncthreads();
        char* vtb = (char*)ws + OFF_VT + (size_t)h * 262144 + (size_t)(c & 31) * 8192;
        #pragma unroll
        for (int k2 = 0; k2 < 2; ++k2) {
            int si = tid + 256 * k2;
            int jh = si >> 8, s = (si >> 6) & 3, l2 = si & 63;
            int lq2 = l2 >> 4, ln2 = l2 & 15;
            u16x8 x = *(const u16x8*)&T[16 * s + ln2][32 * jh + 8 * lq2];
            *(u16x8*)(vtb + (jh * 4 + s) * 1024 + l2 * 16) = x;
        }
    }
}

// ---------------- main kernel: barrier-free loop, coalesced 1KB fragment loads ----------------
// Grid 2048 = head(8, bid&7 for XCD affinity) x p(32) x sub(8) -> 8 blocks/CU.
// launch_bounds stays (256,4): the allocator keeps its 128-VGPR budget (emits ~64,
// proven rounds 5-8), and at VGPR<=64 the HW co-resides 8 blocks/CU = 8 waves/SIMD —
// the grid, not the kernel, was the occupancy limiter (round-3's regression was the
// (256,8) bound forcing VGPR=32 + spill, NOT the 8-way split).
// The 33-iter j-space splits 4/4/4/4/4/4/4/5 across 8 subs; a sub may straddle A/B ->
// <=2 segments, each writing a partial.  Shuffle T-gather (round-6): no Ts LDS.
__global__ __launch_bounds__(256, 4)
void fastmax_main(const ushort_t* __restrict__ wsb, float* __restrict__ outg,
                  float* __restrict__ wsPart)
{
    __shared__ __align__(16) unsigned char U[8704]; // Ws[4][16][40]u16 (5120) | Epi[32][68]f32 (8704)
    float* Epi = (float*)U;
    (void)outg;

    const char* qT = (const char*)wsb + OFF_Q;
    const char* kT = (const char*)wsb + OFF_K;
    const char* vT = (const char*)wsb + OFF_VT;
    const char* rT = (const char*)wsb + OFF_R;

    const int tid = threadIdx.x;
    const int w   = tid >> 6;
    const int l   = tid & 63;
    const int lq  = l >> 4;
    const int ln  = l & 15;
    const int rt  = w & 1;
    const int ch  = w >> 1;
    const int lane16 = l * 16;

    ushort_t* wsW = (ushort_t*)(U + w * 1280);           // Ws[w]: [16][40] u16

    const int head = blockIdx.x & 7;                     // bid%8 -> one head per XCD
    const int rest = blockIdx.x >> 3;
    const int p    = rest & 31;
    const int sub  = rest >> 5;                          // 0..7
    const int tileA = 63 - p;
    const int njtA  = (tileA >> 1) + 1;                  // 17..32
    const int tileB = p;

    const int lo = (33 * sub) >> 3;                      // 0,4,8,12,16,20,24,28
    const int hi = (33 * (sub + 1)) >> 3;                // 4,8,12,16,20,24,28,33

    const char* qh = qT + (size_t)head * 262144;
    const char* kh = kT + (size_t)head * 262144;
    const char* vh = vT + (size_t)head * 262144;

    const int sw = 16 * rt - 32 * ch + 32;   // wave's band-window start (0..48)
    const int stream = head * 32 + p;

    #pragma unroll 1
    for (int seg = 0; seg < 2; ++seg) {
        int tile, jlo, jhi;
        if (seg == 0) { tile = tileA; jlo = lo; jhi = (hi < njtA) ? hi : njtA; }
        else          { tile = tileB; jlo = (lo > njtA ? lo : njtA) - njtA; jhi = hi - njtA; }
        if (jlo >= jhi) continue;            // block-uniform
        const int i0 = tile * 32;

        const char* qp = qh + (size_t)((i0 >> 4) + rt) * 2048 + lane16;
        bf16x8 qf0 = *(const bf16x8*)(qp);
        bf16x8 qf1 = *(const bf16x8*)(qp + 1024);

        // per-segment fragment pointers (advance by fixed strides each iter)
        const char* kp = kh + (size_t)(jlo * 4 + 2 * ch) * 2048 + lane16;
        const char* vp = vh + (size_t)(jlo * 2 + ch) * 4096 + lane16;
        const char* rp = rT + (size_t)(((i0 - jlo * 64 + 1984 + sw) >> 4)) * 2048 + lane16;

        f32x4 acc0 = {0,0,0,0}, acc1 = {0,0,0,0}, acc2 = {0,0,0,0}, acc3 = {0,0,0,0};
        float denv0 = 0.f, denv1 = 0.f, denv2 = 0.f, denv3 = 0.f;

        #pragma unroll 1
        for (int jt = jlo; jt < jhi; ++jt) {
            const int j0 = jt * 64;

            // ---- issue all fragment loads (each = 64 lanes x 16B contiguous)
            bf16x8 b00 = *(const bf16x8*)(kp);
            bf16x8 b01 = *(const bf16x8*)(kp + 1024);
            bf16x8 b10 = *(const bf16x8*)(kp + 2048);
            bf16x8 b11 = *(const bf16x8*)(kp + 3072);
            bf16x8 e0a = *(const bf16x8*)(rp);
            bf16x8 e0b = *(const bf16x8*)(rp + 1024);
            bf16x8 e1a = *(const bf16x8*)(rp + 2048);
            bf16x8 e1b = *(const bf16x8*)(rp + 3072);
            bf16x8 e2a = *(const bf16x8*)(rp + 4096);
            bf16x8 e2b = *(const bf16x8*)(rp + 5120);
            bf16x8 v0  = *(const bf16x8*)(vp);
            bf16x8 v1  = *(const bf16x8*)(vp + 1024);
            bf16x8 v2  = *(const bf16x8*)(vp + 2048);
            bf16x8 v3  = *(const bf16x8*)(vp + 3072);
            kp += 8192; vp += 8192; rp -= 8192;

            // ---- S = Q K^T over wave quadrant
            f32x4 s0 = {0,0,0,0}, s1 = {0,0,0,0};
            s0 = __builtin_amdgcn_mfma_f32_16x16x32_bf16(qf0, b00, s0, 0, 0, 0);
            s0 = __builtin_amdgcn_mfma_f32_16x16x32_bf16(qf1, b01, s0, 0, 0, 0);
            s1 = __builtin_amdgcn_mfma_f32_16x16x32_bf16(qf0, b10, s1, 0, 0, 0);
            s1 = __builtin_amdgcn_mfma_f32_16x16x32_bf16(qf1, b11, s1, 0, 0, 0);

            // ---- T = Q band^T, 3 b-tiles kept in registers (f32, no LDS round-trip)
            f32x4 t0 = {0,0,0,0}, t1 = {0,0,0,0}, t2 = {0,0,0,0};
            t0 = __builtin_amdgcn_mfma_f32_16x16x32_bf16(qf0, e0a, t0, 0, 0, 0);
            t0 = __builtin_amdgcn_mfma_f32_16x16x32_bf16(qf1, e0b, t0, 0, 0, 0);
            t1 = __builtin_amdgcn_mfma_f32_16x16x32_bf16(qf0, e1a, t1, 0, 0, 0);
            t1 = __builtin_amdgcn_mfma_f32_16x16x32_bf16(qf1, e1b, t1, 0, 0, 0);
            t2 = __builtin_amdgcn_mfma_f32_16x16x32_bf16(qf0, e2a, t2, 0, 0, 0);
            t2 = __builtin_amdgcn_mfma_f32_16x16x32_bf16(qf1, e2b, t2, 0, 0, 0);

            // ---- shuffle gather + Taylor weight + mask -> Ws (trunc bf16) + denominator
            // src lane for band value: 16*lq + ((rp2 - ln + 15) & 15); tile select:
            // ct=0 -> (rp2>ln) ? t2 : t1 ; ct=1 -> (rp2>ln) ? t1 : t0
            #pragma unroll
            for (int e = 0; e < 4; ++e) {
                int rp2 = 4 * lq + e;                         // row within strip
                int src = 16 * lq + ((rp2 - ln + 15) & 15);
                float sh0 = __shfl(t0[e], src, 64);
                float sh1 = __shfl(t1[e], src, 64);
                float sh2 = __shfl(t2[e], src, 64);
                bool cond = rp2 > ln;
                float sA = s0[e] + (cond ? sh2 : sh1);        // ct=0, col = ln
                float sB = s1[e] + (cond ? sh1 : sh0);        // ct=1, col = 16+ln
                float wv0 = 1.0f + sA + 0.5f * sA * sA;
                if (j0 + 32 * ch + ln > i0 + 16 * rt + rp2) wv0 = 0.0f;
                union { float f; unsigned u; } u0; u0.f = wv0;
                wsW[rp2 * 40 + ln] = (ushort_t)(u0.u >> 16);         // trunc bf16
                u0.u &= 0xffff0000u;                                 // exact bf16 MFMA sees
                float wv1 = 1.0f + sB + 0.5f * sB * sB;
                if (j0 + 32 * ch + 16 + ln > i0 + 16 * rt + rp2) wv1 = 0.0f;
                union { float f; unsigned u; } u1; u1.f = wv1;
                wsW[rp2 * 40 + 16 + ln] = (ushort_t)(u1.u >> 16);
                u1.u &= 0xffff0000u;
                float de = u0.f + u1.f;
                if (e == 0) denv0 += de; else if (e == 1) denv1 += de;
                else if (e == 2) denv2 += de; else denv3 += de;
            }

            // ---- PV += W * V^T over wave's j-half (K=32)
            {
                bf16x8 af = *(const bf16x8*)&wsW[ln * 40 + 8 * lq];  // wave-private RAW
                acc0 = __builtin_amdgcn_mfma_f32_16x16x32_bf16(af, v0, acc0, 0, 0, 0);
                acc1 = __builtin_amdgcn_mfma_f32_16x16x32_bf16(af, v1, acc1, 0, 0, 0);
                acc2 = __builtin_amdgcn_mfma_f32_16x16x32_bf16(af, v2, acc2, 0, 0, 0);
                acc3 = __builtin_amdgcn_mfma_f32_16x16x32_bf16(af, v3, acc3, 0, 0, 0);
            }
        }

        // ---- reduce denominator across the wave's 16 n-lanes
        #pragma unroll
        for (int off = 1; off <= 8; off <<= 1) {
            denv0 += __shfl_xor(denv0, off);
            denv1 += __shfl_xor(denv1, off);
            denv2 += __shfl_xor(denv2, off);
            denv3 += __shfl_xor(denv3, off);
        }

        // ---- epilogue: combine ch halves in Epi (union with Ws; ordered by barriers)
        __syncthreads();
        if (ch == 0) {
            #pragma unroll
            for (int e = 0; e < 4; ++e) {
                int r = 16 * rt + 4 * lq + e;
                Epi[r * 68 +  0 + ln] = acc0[e];
                Epi[r * 68 + 16 + ln] = acc1[e];
                Epi[r * 68 + 32 + ln] = acc2[e];
                Epi[r * 68 + 48 + ln] = acc3[e];
            }
            if (ln == 0) {
                Epi[(16 * rt + 4 * lq + 0) * 68 + 64] = denv0;
                Epi[(16 * rt + 4 * lq + 1) * 68 + 64] = denv1;
                Epi[(16 * rt + 4 * lq + 2) * 68 + 64] = denv2;
                Epi[(16 * rt + 4 * lq + 3) * 68 + 64] = denv3;
            }
        }
        __syncthreads();
        if (ch == 1) {
            #pragma unroll
            for (int e = 0; e < 4; ++e) {
                int r = 16 * rt + 4 * lq + e;
                Epi[r * 68 +  0 + ln] += acc0[e];
                Epi[r * 68 + 16 + ln] += acc1[e];
                Epi[r * 68 + 32 + ln] += acc2[e];
                Epi[r * 68 + 48 + ln] += acc3[e];
            }
            if (ln == 0) {
                Epi[(16 * rt + 4 * lq + 0) * 68 + 64] += denv0;
                Epi[(16 * rt + 4 * lq + 1) * 68 + 64] += denv1;
                Epi[(16 * rt + 4 * lq + 2) * 68 + 64] += denv2;
                Epi[(16 * rt + 4 * lq + 3) * 68 + 64] += denv3;
            }
        }
        __syncthreads();
        // ---- every segment writes a partial; combine does all division/output
        {
            float* dst = wsPart + ((size_t)((stream * 2 + seg) * 8 + sub)) * (32 * 68);
            for (int idx = tid; idx < 32 * 68; idx += 256) dst[idx] = Epi[idx];
        }
        __syncthreads();   // protect U (Epi) from next segment's Ws writes (loop is barrier-free)
    }
}

// ---------------- combine: sum valid sub-partials per tile, divide, write ----------------
// 512 blocks: one per (stream, tile).
__global__ void combine_kernel(const float* __restrict__ wsPart, float* __restrict__ outg) {
    const int blk  = blockIdx.x >> 1;        // 0..255 = head*32 + p
    const int tsel = blockIdx.x & 1;
    const int head = blk >> 5;
    const int p = blk & 31;
    const int njtA = ((63 - p) >> 1) + 1;
    float* oh = outg + (size_t)head * NN * DD;
    const int tile = tsel ? p : (63 - p);
    const float* base = wsPart + ((size_t)(blk * 2 + tsel)) * 8 * (32 * 68);
    int vmask = 0;
    #pragma unroll
    for (int s = 0; s < 8; ++s) {
        int lo_s = (33 * s) >> 3;
        int hi_s = (33 * (s + 1)) >> 3;
        bool valid = tsel ? (hi_s > njtA) : (lo_s < njtA);
        if (valid) vmask |= 1 << s;
    }
    #pragma unroll
    for (int e2 = 0; e2 < 8; ++e2) {
        int idx = threadIdx.x + 256 * e2;
        int r = idx >> 6, d = idx & 63;
        float num = 0.f, den = 0.f;
        #pragma unroll
        for (int s = 0; s < 8; ++s) {
            if (vmask & (1 << s)) {
                num += base[s * 2176 + r * 68 + d];
                den += base[s * 2176 + r * 68 + 64];
            }
        }
        oh[(size_t)(tile * 32 + r) * DD + d] = num / den;
    }
}

// ---------------- fallback (round-2 proven kernel, no ws) ----------------
__global__ __launch_bounds__(256, 2)
void fastmax_fallback(const float* __restrict__ qg0, const float* __restrict__ kg0,
                      const float* __restrict__ vg0, const float* __restrict__ rg,
                      float* __restrict__ outg)
{
    __shared__ __align__(16) ushort_t Qs[32][72];
    __shared__ __align__(16) ushort_t Ks2[64][72];
    __shared__ __align__(16) ushort_t Bs2[96][72];
    __shared__ __align__(16) ushort_t Vts2[96][72];
    __shared__ __align__(16) float    Tsf[32][97];
    __shared__ __align__(16) ushort_t Wsf[32][72];
    __shared__ float denomLds[32];

    const int tid = threadIdx.x;
    const int w = tid >> 6, l = tid & 63, lq = l >> 4, ln = l & 15;
    const int head = blockIdx.x & 7, ib = blockIdx.x >> 3;
    const int it = 63 - ib, i0 = it * 32, njt = (it >> 1) + 1;
    const float* qg = qg0 + (size_t)head * NN * DD;
    const float* kg = kg0 + (size_t)head * NN * DD;
    const float* vg = vg0 + (size_t)head * NN * DD;
    float* og = outg + (size_t)head * NN * DD;
    {
        #pragma unroll
        for (int p = 0; p < 2; ++p) {
            int c = tid + 256 * p; int r = c >> 4, dc = (c & 15) << 2;
            float4 f = *(const float4*)&qg[(size_t)(i0 + r) * DD + dc];
            ushort4 u; u.x = f2bf(f.x); u.y = f2bf(f.y); u.z = f2bf(f.z); u.w = f2bf(f.w);
            *(ushort4*)&Qs[r][dc] = u;
        }
        for (int idx = tid; idx < 32 * 72; idx += 256) {
            int rr = idx / 72, cc = idx - rr * 72;
            Vts2[64 + rr][cc] = (rr == 0) ? (ushort_t)0x3F80 : (ushort_t)0;
        }
    }
    f32x4 a0 = {0,0,0,0}, a1 = {0,0,0,0}, a2 = {0,0,0,0};
    const int pr = w & 1, rt = w & 1, cp = w >> 1;
    for (int jt = 0; jt < njt; ++jt) {
        const int j0 = jt * 64;
        __syncthreads();
        #pragma unroll
        for (int p = 0; p < 4; ++p) {
            int c = tid + 256 * p; int r = c >> 4, dc = (c & 15) << 2;
            float4 f = *(const float4*)&kg[(size_t)(j0 + r) * DD + dc];
            ushort4 u; u.x = f2bf(f.x); u.y = f2bf(f.y); u.z = f2bf(f.z); u.w = f2bf(f.w);
            *(ushort4*)&Ks2[r][dc] = u;
        }
        const int relbase = i0 - j0 + 1984;
        #pragma unroll
        for (int p = 0; p < 6; ++p) {
            int c = tid + 256 * p; int r = c >> 4, dc = (c & 15) << 2;
            int row = relbase + r; if (row > 4094) row = 4094;
            float4 f = *(const float4*)&rg[(size_t)row * DD + dc];
            ushort4 u; u.x = f2bf(f.x); u.y = f2bf(f.y); u.z = f2bf(f.z); u.w = f2bf(f.w);
            *(ushort4*)&Bs2[r][dc] = u;
        }
        #pragma unroll
        for (int p = 0; p < 4; ++p) {
            int c = tid + 256 * p; int r = c >> 4, dc = (c & 15) << 2;
            float4 f = *(const float4*)&vg[(size_t)(j0 + r) * DD + dc];
            Vts2[dc + 0][r] = f2bf(f.x); Vts2[dc + 1][r] = f2bf(f.y);
            Vts2[dc + 2][r] = f2bf(f.z); Vts2[dc + 3][r] = f2bf(f.w);
        }
        __syncthreads();
        f32x4 s0 = {0,0,0,0}, s1 = {0,0,0,0};
        #pragma unroll
        for (int ks = 0; ks < 2; ++ks) {
            bf16x8 a = *(const bf16x8*)&Qs[16 * rt + ln][32 * ks + 8 * lq];
            bf16x8 b0 = *(const bf16x8*)&Ks2[32 * cp + ln][32 * ks + 8 * lq];
            bf16x8 b1 = *(const bf16x8*)&Ks2[32 * cp + 16 + ln][32 * ks + 8 * lq];
            s0 = __builtin_amdgcn_mfma_f32_16x16x32_bf16(a, b0, s0, 0, 0, 0);
            s1 = __builtin_amdgcn_mfma_f32_16x16x32_bf16(a, b1, s1, 0, 0, 0);
        }
        #pragma unroll
        for (int kk = 0; kk < 3; ++kk) {
            int bt = (w >> 1) + 2 * kk;
            f32x4 t = {0,0,0,0};
            #pragma unroll
            for (int ks = 0; ks < 2; ++ks) {
                bf16x8 a = *(const bf16x8*)&Qs[16 * rt + ln][32 * ks + 8 * lq];
                bf16x8 b = *(const bf16x8*)&Bs2[16 * bt + ln][32 * ks + 8 * lq];
                t = __builtin_amdgcn_mfma_f32_16x16x32_bf16(a, b, t, 0, 0, 0);
            }
            #pragma unroll
            for (int e = 0; e < 4; ++e) Tsf[16 * rt + 4 * lq + e][16 * bt + ln] = t[e];
        }
        __syncthreads();
        #pragma unroll
        for (int ct2 = 0; ct2 < 2; ++ct2) {
            f32x4 sv = ct2 ? s1 : s0;
            int c_loc = 32 * cp + 16 * ct2 + ln, j = j0 + c_loc;
            #pragma unroll
            for (int e = 0; e < 4; ++e) {
                int r_loc = 16 * rt + 4 * lq + e, i = i0 + r_loc;
                float s = sv[e] + Tsf[r_loc][r_loc - c_loc + 63];
                float wv = 1.0f + s + 0.5f * s * s;
                if (j > i) wv = 0.0f;
                Wsf[r_loc][c_loc] = f2bf(wv);
            }
        }
        __syncthreads();
        {
            bf16x8 af0 = *(const bf16x8*)&Wsf[16 * pr + ln][ 0 + 8 * lq];
            bf16x8 af1 = *(const bf16x8*)&Wsf[16 * pr + ln][32 + 8 * lq];
            int pn0 = w >> 1; bf16x8 b;
            b = *(const bf16x8*)&Vts2[16 * (pn0 + 0) + ln][ 0 + 8 * lq];
            a0 = __builtin_amdgcn_mfma_f32_16x16x32_bf16(af0, b, a0, 0, 0, 0);
            b = *(const bf16x8*)&Vts2[16 * (pn0 + 0) + ln][32 + 8 * lq];
            a0 = __builtin_amdgcn_mfma_f32_16x16x32_bf16(af1, b, a0, 0, 0, 0);
            b = *(const bf16x8*)&Vts2[16 * (pn0 + 2) + ln][ 0 + 8 * lq];
            a1 = __builtin_amdgcn_mfma_f32_16x16x32_bf16(af0, b, a1, 0, 0, 0);
            b = *(const bf16x8*)&Vts2[16 * (pn0 + 2) + ln][32 + 8 * lq];
            a1 = __builtin_amdgcn_mfma_f32_16x16x32_bf16(af1, b, a1, 0, 0, 0);
            b = *(const bf16x8*)&Vts2[16 * (pn0 + 4) + ln][ 0 + 8 * lq];
            a2 = __builtin_amdgcn_mfma_f32_16x16x32_bf16(af0, b, a2, 0, 0, 0);
            b = *(const bf16x8*)&Vts2[16 * (pn0 + 4) + ln][32 + 8 * lq];
            a2 = __builtin_amdgcn_mfma_f32_16x16x32_bf16(af1, b, a2, 0, 0, 0);
        }
    }
    if (w < 2 && ln == 0) {
        #pragma unroll
        for (int e = 0; e < 4; ++e) denomLds[16 * pr + 4 * lq + e] = a2[e];
    }
    __syncthreads();
    #pragma unroll
    for (int k = 0; k < 2; ++k) {
        int pn = (w >> 1) + 2 * k;
        f32x4 acc = k ? a1 : a0;
        #pragma unroll
        for (int e = 0; e < 4; ++e) {
            int r_loc = 16 * pr + 4 * lq + e;
            og[(size_t)(i0 + r_loc) * DD + 16 * pn + ln] = acc[e] / denomLds[r_loc];
        }
    }
}

extern "C" void kernel_launch(void* const* d_in, const int* in_sizes, int n_in,
                              void* d_out, int out_size, void* d_ws, size_t ws_size,
                              hipStream_t stream) {
    const float* q   = (const float*)d_in[0];
    const float* k   = (const float*)d_in[1];
    const float* v   = (const float*)d_in[2];
    const float* rpe = (const float*)d_in[3];
    float* out = (float*)d_out;

    if (ws_size >= WS_NEED) {
        ushort_t* wsb = (ushort_t*)d_ws;
        float* wsPart = (float*)((char*)d_ws + OFF_P);
        hipLaunchKernelGGL(pre_kernel, dim3(832), dim3(256), 0, stream,
                           q, k, rpe, v, wsb);
        hipLaunchKernelGGL(fastmax_main, dim3(2048), dim3(256), 0, stream,
                           wsb, out, wsPart);
        hipLaunchKernelGGL(combine_kernel, dim3(512), dim3(256), 0, stream, wsPart, out);
    } else {
        hipLaunchKernelGGL(fastmax_fallback, dim3(512), dim3(256), 0, stream,
                           q, k, v, rpe, out);
    }
}

// Round 10
// 106.608 us; speedup vs baseline: 1.0485x; 1.0485x over previous
//
#include <hip/hip_runtime.h>
#include <hip/hip_bf16.h>

#define HH 8
#define NN 2048
#define DD 64

typedef __attribute__((ext_vector_type(8))) short bf16x8;
typedef __attribute__((ext_vector_type(4))) float f32x4;
typedef __attribute__((ext_vector_type(8))) unsigned short u16x8;
typedef unsigned short ushort_t;

static __device__ __forceinline__ unsigned short f2bf(float x) {
    union { float f; unsigned u; } un; un.f = x;
    unsigned r = un.u + 0x7FFFu + ((un.u >> 16) & 1u);  // RNE
    return (unsigned short)(r >> 16);
}
static __device__ __forceinline__ float bf2f(unsigned short u) {
    union { unsigned u; float f; } un; un.u = ((unsigned)u) << 16;
    return un.f;
}

// ---------------- ws layout (bytes) ----------------
// All of Q/K/VT/R are stored as FRAGMENT-MAJOR 1KB tiles: a tile is 16 rows x 32 cols
// (bf16); byte slot l*16 holds row (l&15), cols 8*(l>>4)..+8 -- exactly the 16B one
// MFMA lane consumes.  In-loop loads are therefore base + l*16 (fully coalesced 1KB).
#define OFF_Q  0u          // [head][jtile 0..127][dh 0..1] 1KB tiles   (2MB)
#define OFF_K  2097152u    // same geometry                              (2MB)
#define OFF_VT 4194304u    // [head][j32 0..63][s 0..3] 1KB tiles        (2MB)
#define OFF_R  6291456u    // [rtile 0..255][dh 0..1] 1KB tiles          (512KB)
#define OFF_P  6815744u    // partials: [256 streams][2 tiles][4 subs][32][68] f32
#define WS_NEED 24641536u

// ---------------- pre-pass: f32 -> bf16 fragment tiles (4x coarsened) ----------------
// blocks: [0,576) handle FOUR Q/K/rpe 16x64 tiles each (tile ids 4b..4b+3 in [0,2304):
// [0,1024) Q, [1024,2048) K, [2048,2304) rpe); [576,832) V chunks (64x64 transpose).
__global__ void pre_kernel(const float* __restrict__ q, const float* __restrict__ k,
                           const float* __restrict__ r, const float* __restrict__ v,
                           ushort_t* __restrict__ ws) {
    __shared__ __align__(16) ushort_t T[64][72];
    const int tid = threadIdx.x;
    const int b = blockIdx.x;
    if (b < 576) {
        // ---- four 16x64 tiles -> eight 1KB fragment tiles
        char* dsts[4];
        const int rr = tid >> 4, dc = (tid & 15) << 2;
        #pragma unroll
        for (int p = 0; p < 4; ++p) {
            const int t = 4 * b + p;
            const float* srcrow;
            char* dst;
            int row = rr;
            if (t < 1024) {
                int head = t >> 7, tile = t & 127;
                srcrow = q + ((size_t)head * NN + (size_t)tile * 16) * DD;
                dst = (char*)ws + OFF_Q + (size_t)head * 262144 + (size_t)tile * 2048;
            } else if (t < 2048) {
                int tt = t - 1024; int head = tt >> 7, tile = tt & 127;
                srcrow = k + ((size_t)head * NN + (size_t)tile * 16) * DD;
                dst = (char*)ws + OFF_K + (size_t)head * 262144 + (size_t)tile * 2048;
            } else {
                int tile = t - 2048;
                dst = (char*)ws + OFF_R + (size_t)tile * 2048;
                int gr = tile * 16 + rr; if (gr > 4094) gr = 4094;   // bake the clamp
                srcrow = r + (size_t)gr * DD; row = 0;
            }
            float4 f = *(const float4*)&srcrow[(size_t)row * DD + dc];
            T[16 * p + rr][dc + 0] = f2bf(f.x); T[16 * p + rr][dc + 1] = f2bf(f.y);
            T[16 * p + rr][dc + 2] = f2bf(f.z); T[16 * p + rr][dc + 3] = f2bf(f.w);
            dsts[p] = dst;
        }
        __syncthreads();
        if (tid < 128) {
            const int dh = tid >> 6, l = tid & 63, lq = l >> 4, ln = l & 15;
            #pragma unroll
            for (int p = 0; p < 4; ++p) {
                u16x8 x = *(const u16x8*)&T[16 * p + ln][32 * dh + 8 * lq];
                *(u16x8*)(dsts[p] + dh * 1024 + l * 16) = x;
            }
        }
    } else {
        // ---- V chunk: 64 rows (j) x 64 cols (d) -> transpose -> 8 fragment tiles
        const int c = b - 576;
        const int h = c >> 5;
        const int n0 = (c & 31) * 64;
        const float* vh = v + (size_t)h * NN * DD;
        #pragma unroll
        for (int p = 0; p < 4; ++p) {
            int c2 = tid + 256 * p; int rr = c2 >> 4, dc = (c2 & 15) << 2;
            float4 f = *(const float4*)&vh[(size_t)(n0 + rr) * DD + dc];
            T[dc + 0][rr] = f2bf(f.x); T[dc + 1][rr] = f2bf(f.y);
            T[dc + 2][rr] = f2bf(f.z); T[dc + 3][rr] = f2bf(f.w);
        }
        __syncthreads();
        char* vtb = (char*)ws + OFF_VT + (size_t)h * 262144 + (size_t)(c & 31) * 8192;
        #pragma unroll
        for (int k2 = 0; k2 < 2; ++k2) {
            int si = tid + 256 * k2;
            int jh = si >> 8, s = (si >> 6) & 3, l2 = si & 63;
            int lq2 = l2 >> 4, ln2 = l2 & 15;
            u16x8 x = *(const u16x8*)&T[16 * s + ln2][32 * jh + 8 * lq2];
            *(u16x8*)(vtb + (jh * 4 + s) * 1024 + l2 * 16) = x;
        }
    }
}

// ---------------- main kernel: barrier-free loop, coalesced 1KB fragment loads ----------------
// Round-8 champion structure (grid 1024 = head x p x sub(4), 4 blocks/CU, VGPR~64,
// shuffle T-gather, no Ts LDS).  Added: s_setprio(1) around the MFMA clusters —
// waves here are barrier-free/independent-phase, the regime where setprio measured
// positive (attn m191); it was only null/negative in barrier-lockstep loops (m190).
__global__ __launch_bounds__(256, 4)
void fastmax_main(const ushort_t* __restrict__ wsb, float* __restrict__ outg,
                  float* __restrict__ wsPart)
{
    __shared__ __align__(16) unsigned char U[8704]; // Ws[4][16][40]u16 (5120) | Epi[32][68]f32 (8704)
    float* Epi = (float*)U;
    (void)outg;

    const char* qT = (const char*)wsb + OFF_Q;
    const char* kT = (const char*)wsb + OFF_K;
    const char* vT = (const char*)wsb + OFF_VT;
    const char* rT = (const char*)wsb + OFF_R;

    const int tid = threadIdx.x;
    const int w   = tid >> 6;
    const int l   = tid & 63;
    const int lq  = l >> 4;
    const int ln  = l & 15;
    const int rt  = w & 1;
    const int ch  = w >> 1;
    const int lane16 = l * 16;

    ushort_t* wsW = (ushort_t*)(U + w * 1280);           // Ws[w]: [16][40] u16

    const int head = blockIdx.x & 7;                     // bid%8 -> one head per XCD
    const int rest = blockIdx.x >> 3;
    const int p    = rest & 31;
    const int sub  = rest >> 5;                          // 0..3
    const int tileA = 63 - p;
    const int njtA  = (tileA >> 1) + 1;                  // 17..32
    const int tileB = p;

    const int lo = (33 * sub + 3) >> 2;                              // 0,9,17,25
    const int hi = (sub == 3) ? 33 : ((33 * (sub + 1) + 3) >> 2);    // 9,17,25,33

    const char* qh = qT + (size_t)head * 262144;
    const char* kh = kT + (size_t)head * 262144;
    const char* vh = vT + (size_t)head * 262144;

    const int sw = 16 * rt - 32 * ch + 32;   // wave's band-window start (0..48)
    const int stream = head * 32 + p;

    #pragma unroll 1
    for (int seg = 0; seg < 2; ++seg) {
        int tile, jlo, jhi;
        if (seg == 0) { tile = tileA; jlo = lo; jhi = (hi < njtA) ? hi : njtA; }
        else          { tile = tileB; jlo = (lo > njtA ? lo : njtA) - njtA; jhi = hi - njtA; }
        if (jlo >= jhi) continue;            // block-uniform
        const int i0 = tile * 32;

        const char* qp = qh + (size_t)((i0 >> 4) + rt) * 2048 + lane16;
        bf16x8 qf0 = *(const bf16x8*)(qp);
        bf16x8 qf1 = *(const bf16x8*)(qp + 1024);

        // per-segment fragment pointers (advance by fixed strides each iter)
        const char* kp = kh + (size_t)(jlo * 4 + 2 * ch) * 2048 + lane16;
        const char* vp = vh + (size_t)(jlo * 2 + ch) * 4096 + lane16;
        const char* rp = rT + (size_t)(((i0 - jlo * 64 + 1984 + sw) >> 4)) * 2048 + lane16;

        f32x4 acc0 = {0,0,0,0}, acc1 = {0,0,0,0}, acc2 = {0,0,0,0}, acc3 = {0,0,0,0};
        float denv0 = 0.f, denv1 = 0.f, denv2 = 0.f, denv3 = 0.f;

        #pragma unroll 1
        for (int jt = jlo; jt < jhi; ++jt) {
            const int j0 = jt * 64;

            // ---- issue all fragment loads (each = 64 lanes x 16B contiguous)
            bf16x8 b00 = *(const bf16x8*)(kp);
            bf16x8 b01 = *(const bf16x8*)(kp + 1024);
            bf16x8 b10 = *(const bf16x8*)(kp + 2048);
            bf16x8 b11 = *(const bf16x8*)(kp + 3072);
            bf16x8 e0a = *(const bf16x8*)(rp);
            bf16x8 e0b = *(const bf16x8*)(rp + 1024);
            bf16x8 e1a = *(const bf16x8*)(rp + 2048);
            bf16x8 e1b = *(const bf16x8*)(rp + 3072);
            bf16x8 e2a = *(const bf16x8*)(rp + 4096);
            bf16x8 e2b = *(const bf16x8*)(rp + 5120);
            bf16x8 v0  = *(const bf16x8*)(vp);
            bf16x8 v1  = *(const bf16x8*)(vp + 1024);
            bf16x8 v2  = *(const bf16x8*)(vp + 2048);
            bf16x8 v3  = *(const bf16x8*)(vp + 3072);
            kp += 8192; vp += 8192; rp -= 8192;

            // ---- S = Q K^T + T = Q band^T (MFMA cluster, prio-boosted)
            __builtin_amdgcn_s_setprio(1);
            f32x4 s0 = {0,0,0,0}, s1 = {0,0,0,0};
            s0 = __builtin_amdgcn_mfma_f32_16x16x32_bf16(qf0, b00, s0, 0, 0, 0);
            s0 = __builtin_amdgcn_mfma_f32_16x16x32_bf16(qf1, b01, s0, 0, 0, 0);
            s1 = __builtin_amdgcn_mfma_f32_16x16x32_bf16(qf0, b10, s1, 0, 0, 0);
            s1 = __builtin_amdgcn_mfma_f32_16x16x32_bf16(qf1, b11, s1, 0, 0, 0);

            f32x4 t0 = {0,0,0,0}, t1 = {0,0,0,0}, t2 = {0,0,0,0};
            t0 = __builtin_amdgcn_mfma_f32_16x16x32_bf16(qf0, e0a, t0, 0, 0, 0);
            t0 = __builtin_amdgcn_mfma_f32_16x16x32_bf16(qf1, e0b, t0, 0, 0, 0);
            t1 = __builtin_amdgcn_mfma_f32_16x16x32_bf16(qf0, e1a, t1, 0, 0, 0);
            t1 = __builtin_amdgcn_mfma_f32_16x16x32_bf16(qf1, e1b, t1, 0, 0, 0);
            t2 = __builtin_amdgcn_mfma_f32_16x16x32_bf16(qf0, e2a, t2, 0, 0, 0);
            t2 = __builtin_amdgcn_mfma_f32_16x16x32_bf16(qf1, e2b, t2, 0, 0, 0);
            __builtin_amdgcn_s_setprio(0);

            // ---- shuffle gather + Taylor weight + mask -> Ws (trunc bf16) + denominator
            // src lane for band value: 16*lq + ((rp2 - ln + 15) & 15); tile select:
            // ct=0 -> (rp2>ln) ? t2 : t1 ; ct=1 -> (rp2>ln) ? t1 : t0
            #pragma unroll
            for (int e = 0; e < 4; ++e) {
                int rp2 = 4 * lq + e;                         // row within strip
                int src = 16 * lq + ((rp2 - ln + 15) & 15);
                float sh0 = __shfl(t0[e], src, 64);
                float sh1 = __shfl(t1[e], src, 64);
                float sh2 = __shfl(t2[e], src, 64);
                bool cond = rp2 > ln;
                float sA = s0[e] + (cond ? sh2 : sh1);        // ct=0, col = ln
                float sB = s1[e] + (cond ? sh1 : sh0);        // ct=1, col = 16+ln
                float wv0 = 1.0f + sA + 0.5f * sA * sA;
                if (j0 + 32 * ch + ln > i0 + 16 * rt + rp2) wv0 = 0.0f;
                union { float f; unsigned u; } u0; u0.f = wv0;
                wsW[rp2 * 40 + ln] = (ushort_t)(u0.u >> 16);         // trunc bf16
                u0.u &= 0xffff0000u;                                 // exact bf16 MFMA sees
                float wv1 = 1.0f + sB + 0.5f * sB * sB;
                if (j0 + 32 * ch + 16 + ln > i0 + 16 * rt + rp2) wv1 = 0.0f;
                union { float f; unsigned u; } u1; u1.f = wv1;
                wsW[rp2 * 40 + 16 + ln] = (ushort_t)(u1.u >> 16);
                u1.u &= 0xffff0000u;
                float de = u0.f + u1.f;
                if (e == 0) denv0 += de; else if (e == 1) denv1 += de;
                else if (e == 2) denv2 += de; else denv3 += de;
            }

            // ---- PV += W * V^T over wave's j-half (K=32), prio-boosted
            {
                bf16x8 af = *(const bf16x8*)&wsW[ln * 40 + 8 * lq];  // wave-private RAW
                __builtin_amdgcn_s_setprio(1);
                acc0 = __builtin_amdgcn_mfma_f32_16x16x32_bf16(af, v0, acc0, 0, 0, 0);
                acc1 = __builtin_amdgcn_mfma_f32_16x16x32_bf16(af, v1, acc1, 0, 0, 0);
                acc2 = __builtin_amdgcn_mfma_f32_16x16x32_bf16(af, v2, acc2, 0, 0, 0);
                acc3 = __builtin_amdgcn_mfma_f32_16x16x32_bf16(af, v3, acc3, 0, 0, 0);
                __builtin_amdgcn_s_setprio(0);
            }
        }

        // ---- reduce denominator across the wave's 16 n-lanes
        #pragma unroll
        for (int off = 1; off <= 8; off <<= 1) {
            denv0 += __shfl_xor(denv0, off);
            denv1 += __shfl_xor(denv1, off);
            denv2 += __shfl_xor(denv2, off);
            denv3 += __shfl_xor(denv3, off);
        }

        // ---- epilogue: combine ch halves in Epi (union with Ws; ordered by barriers)
        __syncthreads();
        if (ch == 0) {
            #pragma unroll
            for (int e = 0; e < 4; ++e) {
                int r = 16 * rt + 4 * lq + e;
                Epi[r * 68 +  0 + ln] = acc0[e];
                Epi[r * 68 + 16 + ln] = acc1[e];
                Epi[r * 68 + 32 + ln] = acc2[e];
                Epi[r * 68 + 48 + ln] = acc3[e];
            }
            if (ln == 0) {
                Epi[(16 * rt + 4 * lq + 0) * 68 + 64] = denv0;
                Epi[(16 * rt + 4 * lq + 1) * 68 + 64] = denv1;
                Epi[(16 * rt + 4 * lq + 2) * 68 + 64] = denv2;
                Epi[(16 * rt + 4 * lq + 3) * 68 + 64] = denv3;
            }
        }
        __syncthreads();
        if (ch == 1) {
            #pragma unroll
            for (int e = 0; e < 4; ++e) {
                int r = 16 * rt + 4 * lq + e;
                Epi[r * 68 +  0 + ln] += acc0[e];
                Epi[r * 68 + 16 + ln] += acc1[e];
                Epi[r * 68 + 32 + ln] += acc2[e];
                Epi[r * 68 + 48 + ln] += acc3[e];
            }
            if (ln == 0) {
                Epi[(16 * rt + 4 * lq + 0) * 68 + 64] += denv0;
                Epi[(16 * rt + 4 * lq + 1) * 68 + 64] += denv1;
                Epi[(16 * rt + 4 * lq + 2) * 68 + 64] += denv2;
                Epi[(16 * rt + 4 * lq + 3) * 68 + 64] += denv3;
            }
        }
        __syncthreads();
        // ---- every segment writes a partial; combine does all division/output
        {
            float* dst = wsPart + ((size_t)((stream * 2 + seg) * 4 + sub)) * (32 * 68);
            for (int idx = tid; idx < 32 * 68; idx += 256) dst[idx] = Epi[idx];
        }
        __syncthreads();   // protect U (Epi) from next segment's Ws writes (loop is barrier-free)
    }
}

// ---------------- combine: sum valid sub-partials per tile, divide, write ----------------
// 512 blocks, HEAD-AFFINE: head = bid&7 so each combine block lands on the XCD whose
// main blocks wrote that head's partials (2.2MB/head << 4MB per-XCD L2) -> L2 hits.
__global__ void combine_kernel(const float* __restrict__ wsPart, float* __restrict__ outg) {
    const int head = blockIdx.x & 7;
    const int idx6 = blockIdx.x >> 3;        // 0..63
    const int p    = idx6 >> 1;              // 0..31
    const int tsel = idx6 & 1;
    const int blk  = head * 32 + p;          // stream
    const int njtA = ((63 - p) >> 1) + 1;
    float* oh = outg + (size_t)head * NN * DD;
    const int tile = tsel ? p : (63 - p);
    const float* base = wsPart + ((size_t)(blk * 2 + tsel)) * 4 * (32 * 68);
    int vmask = 0;
    #pragma unroll
    for (int s = 0; s < 4; ++s) {
        int lo_s = (33 * s + 3) >> 2;
        int hi_s = (s == 3) ? 33 : ((33 * (s + 1) + 3) >> 2);
        bool valid = tsel ? (hi_s > njtA) : (lo_s < njtA);
        if (valid) vmask |= 1 << s;
    }
    #pragma unroll
    for (int e2 = 0; e2 < 8; ++e2) {
        int idx = threadIdx.x + 256 * e2;
        int r = idx >> 6, d = idx & 63;
        float num = 0.f, den = 0.f;
        #pragma unroll
        for (int s = 0; s < 4; ++s) {
            if (vmask & (1 << s)) {
                num += base[s * 2176 + r * 68 + d];
                den += base[s * 2176 + r * 68 + 64];
            }
        }
        oh[(size_t)(tile * 32 + r) * DD + d] = num / den;
    }
}

// ---------------- fallback (round-2 proven kernel, no ws) ----------------
__global__ __launch_bounds__(256, 2)
void fastmax_fallback(const float* __restrict__ qg0, const float* __restrict__ kg0,
                      const float* __restrict__ vg0, const float* __restrict__ rg,
                      float* __restrict__ outg)
{
    __shared__ __align__(16) ushort_t Qs[32][72];
    __shared__ __align__(16) ushort_t Ks2[64][72];
    __shared__ __align__(16) ushort_t Bs2[96][72];
    __shared__ __align__(16) ushort_t Vts2[96][72];
    __shared__ __align__(16) float    Tsf[32][97];
    __shared__ __align__(16) ushort_t Wsf[32][72];
    __shared__ float denomLds[32];

    const int tid = threadIdx.x;
    const int w = tid >> 6, l = tid & 63, lq = l >> 4, ln = l & 15;
    const int head = blockIdx.x & 7, ib = blockIdx.x >> 3;
    const int it = 63 - ib, i0 = it * 32, njt = (it >> 1) + 1;
    const float* qg = qg0 + (size_t)head * NN * DD;
    const float* kg = kg0 + (size_t)head * NN * DD;
    const float* vg = vg0 + (size_t)head * NN * DD;
    float* og = outg + (size_t)head * NN * DD;
    {
        #pragma unroll
        for (int p = 0; p < 2; ++p) {
            int c = tid + 256 * p; int r = c >> 4, dc = (c & 15) << 2;
            float4 f = *(const float4*)&qg[(size_t)(i0 + r) * DD + dc];
            ushort4 u; u.x = f2bf(f.x); u.y = f2bf(f.y); u.z = f2bf(f.z); u.w = f2bf(f.w);
            *(ushort4*)&Qs[r][dc] = u;
        }
        for (int idx = tid; idx < 32 * 72; idx += 256) {
            int rr = idx / 72, cc = idx - rr * 72;
            Vts2[64 + rr][cc] = (rr == 0) ? (ushort_t)0x3F80 : (ushort_t)0;
        }
    }
    f32x4 a0 = {0,0,0,0}, a1 = {0,0,0,0}, a2 = {0,0,0,0};
    const int pr = w & 1, rt = w & 1, cp = w >> 1;
    for (int jt = 0; jt < njt; ++jt) {
        const int j0 = jt * 64;
        __syncthreads();
        #pragma unroll
        for (int p = 0; p < 4; ++p) {
            int c = tid + 256 * p; int r = c >> 4, dc = (c & 15) << 2;
            float4 f = *(const float4*)&kg[(size_t)(j0 + r) * DD + dc];
            ushort4 u; u.x = f2bf(f.x); u.y = f2bf(f.y); u.z = f2bf(f.z); u.w = f2bf(f.w);
            *(ushort4*)&Ks2[r][dc] = u;
        }
        const int relbase = i0 - j0 + 1984;
        #pragma unroll
        for (int p = 0; p < 6; ++p) {
            int c = tid + 256 * p; int r = c >> 4, dc = (c & 15) << 2;
            int row = relbase + r; if (row > 4094) row = 4094;
            float4 f = *(const float4*)&rg[(size_t)row * DD + dc];
            ushort4 u; u.x = f2bf(f.x); u.y = f2bf(f.y); u.z = f2bf(f.z); u.w = f2bf(f.w);
            *(ushort4*)&Bs2[r][dc] = u;
        }
        #pragma unroll
        for (int p = 0; p < 4; ++p) {
            int c = tid + 256 * p; int r = c >> 4, dc = (c & 15) << 2;
            float4 f = *(const float4*)&vg[(size_t)(j0 + r) * DD + dc];
            Vts2[dc + 0][r] = f2bf(f.x); Vts2[dc + 1][r] = f2bf(f.y);
            Vts2[dc + 2][r] = f2bf(f.z); Vts2[dc + 3][r] = f2bf(f.w);
        }
        __syncthreads();
        f32x4 s0 = {0,0,0,0}, s1 = {0,0,0,0};
        #pragma unroll
        for (int ks = 0; ks < 2; ++ks) {
            bf16x8 a = *(const bf16x8*)&Qs[16 * rt + ln][32 * ks + 8 * lq];
            bf16x8 b0 = *(const bf16x8*)&Ks2[32 * cp + ln][32 * ks + 8 * lq];
            bf16x8 b1 = *(const bf16x8*)&Ks2[32 * cp + 16 + ln][32 * ks + 8 * lq];
            s0 = __builtin_amdgcn_mfma_f32_16x16x32_bf16(a, b0, s0, 0, 0, 0);
            s1 = __builtin_amdgcn_mfma_f32_16x16x32_bf16(a, b1, s1, 0, 0, 0);
        }
        #pragma unroll
        for (int kk = 0; kk < 3; ++kk) {
            int bt = (w >> 1) + 2 * kk;
            f32x4 t = {0,0,0,0};
            #pragma unroll
            for (int ks = 0; ks < 2; ++ks) {
                bf16x8 a = *(const bf16x8*)&Qs[16 * rt + ln][32 * ks + 8 * lq];
                bf16x8 b = *(const bf16x8*)&Bs2[16 * bt + ln][32 * ks + 8 * lq];
                t = __builtin_amdgcn_mfma_f32_16x16x32_bf16(a, b, t, 0, 0, 0);
            }
            #pragma unroll
            for (int e = 0; e < 4; ++e) Tsf[16 * rt + 4 * lq + e][16 * bt + ln] = t[e];
        }
        __syncthreads();
        #pragma unroll
        for (int ct2 = 0; ct2 < 2; ++ct2) {
            f32x4 sv = ct2 ? s1 : s0;
            int c_loc = 32 * cp + 16 * ct2 + ln, j = j0 + c_loc;
            #pragma unroll
            for (int e = 0; e < 4; ++e) {
                int r_loc = 16 * rt + 4 * lq + e, i = i0 + r_loc;
                float s = sv[e] + Tsf[r_loc][r_loc - c_loc + 63];
                float wv = 1.0f + s + 0.5f * s * s;
                if (j > i) wv = 0.0f;
                Wsf[r_loc][c_loc] = f2bf(wv);
            }
        }
        __syncthreads();
        {
            bf16x8 af0 = *(const bf16x8*)&Wsf[16 * pr + ln][ 0 + 8 * lq];
            bf16x8 af1 = *(const bf16x8*)&Wsf[16 * pr + ln][32 + 8 * lq];
            int pn0 = w >> 1; bf16x8 b;
            b = *(const bf16x8*)&Vts2[16 * (pn0 + 0) + ln][ 0 + 8 * lq];
            a0 = __builtin_amdgcn_mfma_f32_16x16x32_bf16(af0, b, a0, 0, 0, 0);
            b = *(const bf16x8*)&Vts2[16 * (pn0 + 0) + ln][32 + 8 * lq];
            a0 = __builtin_amdgcn_mfma_f32_16x16x32_bf16(af1, b, a0, 0, 0, 0);
            b = *(const bf16x8*)&Vts2[16 * (pn0 + 2) + ln][ 0 + 8 * lq];
            a1 = __builtin_amdgcn_mfma_f32_16x16x32_bf16(af0, b, a1, 0, 0, 0);
            b = *(const bf16x8*)&Vts2[16 * (pn0 + 2) + ln][32 + 8 * lq];
            a1 = __builtin_amdgcn_mfma_f32_16x16x32_bf16(af1, b, a1, 0, 0, 0);
            b = *(const bf16x8*)&Vts2[16 * (pn0 + 4) + ln][ 0 + 8 * lq];
            a2 = __builtin_amdgcn_mfma_f32_16x16x32_bf16(af0, b, a2, 0, 0, 0);
            b = *(const bf16x8*)&Vts2[16 * (pn0 + 4) + ln][32 + 8 * lq];
            a2 = __builtin_amdgcn_mfma_f32_16x16x32_bf16(af1, b, a2, 0, 0, 0);
        }
    }
    if (w < 2 && ln == 0) {
        #pragma unroll
        for (int e = 0; e < 4; ++e) denomLds[16 * pr + 4 * lq + e] = a2[e];
    }
    __syncthreads();
    #pragma unroll
    for (int k = 0; k < 2; ++k) {
        int pn = (w >> 1) + 2 * k;
        f32x4 acc = k ? a1 : a0;
        #pragma unroll
        for (int e = 0; e < 4; ++e) {
            int r_loc = 16 * pr + 4 * lq + e;
            og[(size_t)(i0 + r_loc) * DD + 16 * pn + ln] = acc[e] / denomLds[r_loc];
        }
    }
}

extern "C" void kernel_launch(void* const* d_in, const int* in_sizes, int n_in,
                              void* d_out, int out_size, void* d_ws, size_t ws_size,
                              hipStream_t stream) {
    const float* q   = (const float*)d_in[0];
    const float* k   = (const float*)d_in[1];
    const float* v   = (const float*)d_in[2];
    const float* rpe = (const float*)d_in[3];
    float* out = (float*)d_out;

    if (ws_size >= WS_NEED) {
        ushort_t* wsb = (ushort_t*)d_ws;
        float* wsPart = (float*)((char*)d_ws + OFF_P);
        hipLaunchKernelGGL(pre_kernel, dim3(832), dim3(256), 0, stream,
                           q, k, rpe, v, wsb);
        hipLaunchKernelGGL(fastmax_main, dim3(1024), dim3(256), 0, stream,
                           wsb, out, wsPart);
        hipLaunchKernelGGL(combine_kernel, dim3(512), dim3(256), 0, stream, wsPart, out);
    } else {
        hipLaunchKernelGGL(fastmax_fallback, dim3(512), dim3(256), 0, stream,
                           q, k, v, rpe, out);
    }
}

// Round 11
// 103.046 us; speedup vs baseline: 1.0848x; 1.0346x over previous
//
#include <hip/hip_runtime.h>
#include <hip/hip_bf16.h>

#define HH 8
#define NN 2048
#define DD 64

typedef __attribute__((ext_vector_type(8))) short bf16x8;
typedef __attribute__((ext_vector_type(4))) float f32x4;
typedef __attribute__((ext_vector_type(8))) unsigned short u16x8;
typedef unsigned short ushort_t;

static __device__ __forceinline__ unsigned short f2bf(float x) {
    union { float f; unsigned u; } un; un.f = x;
    unsigned r = un.u + 0x7FFFu + ((un.u >> 16) & 1u);  // RNE
    return (unsigned short)(r >> 16);
}
static __device__ __forceinline__ float bf2f(unsigned short u) {
    union { unsigned u; float f; } un; un.u = ((unsigned)u) << 16;
    return un.f;
}

// ---------------- ws layout (bytes) ----------------
// All of Q/K/VT/R are stored as FRAGMENT-MAJOR 1KB tiles: a tile is 16 rows x 32 cols
// (bf16); byte slot l*16 holds row (l&15), cols 8*(l>>4)..+8 -- exactly the 16B one
// MFMA lane consumes.  In-loop loads are therefore base + l*16 (fully coalesced 1KB).
#define OFF_Q  0u          // [head][jtile 0..127][dh 0..1] 1KB tiles   (2MB)
#define OFF_K  2097152u    // same geometry                              (2MB)
#define OFF_VT 4194304u    // [head][j32 0..63][s 0..3] 1KB tiles        (2MB)
#define OFF_R  6291456u    // [rtile 0..255][dh 0..1] 1KB tiles          (512KB)
#define OFF_P  6815744u    // partials: [256 streams][2 tiles][4 subs][32][68] f32
#define WS_NEED 24641536u

// ---------------- pre-pass: f32 -> bf16 fragment tiles (4x coarsened) ----------------
// blocks: [0,576) handle FOUR Q/K/rpe 16x64 tiles each (tile ids 4b..4b+3 in [0,2304):
// [0,1024) Q, [1024,2048) K, [2048,2304) rpe); [576,832) V chunks (64x64 transpose).
__global__ void pre_kernel(const float* __restrict__ q, const float* __restrict__ k,
                           const float* __restrict__ r, const float* __restrict__ v,
                           ushort_t* __restrict__ ws) {
    __shared__ __align__(16) ushort_t T[64][72];
    const int tid = threadIdx.x;
    const int b = blockIdx.x;
    if (b < 576) {
        // ---- four 16x64 tiles -> eight 1KB fragment tiles
        char* dsts[4];
        const int rr = tid >> 4, dc = (tid & 15) << 2;
        #pragma unroll
        for (int p = 0; p < 4; ++p) {
            const int t = 4 * b + p;
            const float* srcrow;
            char* dst;
            int row = rr;
            if (t < 1024) {
                int head = t >> 7, tile = t & 127;
                srcrow = q + ((size_t)head * NN + (size_t)tile * 16) * DD;
                dst = (char*)ws + OFF_Q + (size_t)head * 262144 + (size_t)tile * 2048;
            } else if (t < 2048) {
                int tt = t - 1024; int head = tt >> 7, tile = tt & 127;
                srcrow = k + ((size_t)head * NN + (size_t)tile * 16) * DD;
                dst = (char*)ws + OFF_K + (size_t)head * 262144 + (size_t)tile * 2048;
            } else {
                int tile = t - 2048;
                dst = (char*)ws + OFF_R + (size_t)tile * 2048;
                int gr = tile * 16 + rr; if (gr > 4094) gr = 4094;   // bake the clamp
                srcrow = r + (size_t)gr * DD; row = 0;
            }
            float4 f = *(const float4*)&srcrow[(size_t)row * DD + dc];
            T[16 * p + rr][dc + 0] = f2bf(f.x); T[16 * p + rr][dc + 1] = f2bf(f.y);
            T[16 * p + rr][dc + 2] = f2bf(f.z); T[16 * p + rr][dc + 3] = f2bf(f.w);
            dsts[p] = dst;
        }
        __syncthreads();
        if (tid < 128) {
            const int dh = tid >> 6, l = tid & 63, lq = l >> 4, ln = l & 15;
            #pragma unroll
            for (int p = 0; p < 4; ++p) {
                u16x8 x = *(const u16x8*)&T[16 * p + ln][32 * dh + 8 * lq];
                *(u16x8*)(dsts[p] + dh * 1024 + l * 16) = x;
            }
        }
    } else {
        // ---- V chunk: 64 rows (j) x 64 cols (d) -> transpose -> 8 fragment tiles
        const int c = b - 576;
        const int h = c >> 5;
        const int n0 = (c & 31) * 64;
        const float* vh = v + (size_t)h * NN * DD;
        #pragma unroll
        for (int p = 0; p < 4; ++p) {
            int c2 = tid + 256 * p; int rr = c2 >> 4, dc = (c2 & 15) << 2;
            float4 f = *(const float4*)&vh[(size_t)(n0 + rr) * DD + dc];
            T[dc + 0][rr] = f2bf(f.x); T[dc + 1][rr] = f2bf(f.y);
            T[dc + 2][rr] = f2bf(f.z); T[dc + 3][rr] = f2bf(f.w);
        }
        __syncthreads();
        char* vtb = (char*)ws + OFF_VT + (size_t)h * 262144 + (size_t)(c & 31) * 8192;
        #pragma unroll
        for (int k2 = 0; k2 < 2; ++k2) {
            int si = tid + 256 * k2;
            int jh = si >> 8, s = (si >> 6) & 3, l2 = si & 63;
            int lq2 = l2 >> 4, ln2 = l2 & 15;
            u16x8 x = *(const u16x8*)&T[16 * s + ln2][32 * jh + 8 * lq2];
            *(u16x8*)(vtb + (jh * 4 + s) * 1024 + l2 * 16) = x;
        }
    }
}

// ---------------- main kernel: barrier-free loop, coalesced 1KB fragment loads ----------------
// Champion structure (round 8): grid 1024 = head(8, bid&7 for XCD affinity) x p(32) x
// sub(4) -> 4 blocks/CU, VGPR~64, shuffle T-gather (no Ts LDS round-trip):
//   T-MFMA output t_bt[e] for band row bw lives in lane 16*lq + (bw&15), element e=rp2&3
//   (same lq as the reader).  bw&15 = (rp2-ln+15)&15 for BOTH ct halves, and the tile
//   select collapses to (rp2 > ln) ? {t2,t1} : {t1,t0}.  T stays f32 (more accurate).
// Only LDS: wave-private Ws (PV A-operand relayout) union'd with Epi (8704 B).
// Rounds 9/10 measured the 8-sub split and setprio/affine-combine tweaks as
// neutral-to-negative; this is the proven local optimum of the structure.
__global__ __launch_bounds__(256, 4)
void fastmax_main(const ushort_t* __restrict__ wsb, float* __restrict__ outg,
                  float* __restrict__ wsPart)
{
    __shared__ __align__(16) unsigned char U[8704]; // Ws[4][16][40]u16 (5120) | Epi[32][68]f32 (8704)
    float* Epi = (float*)U;
    (void)outg;

    const char* qT = (const char*)wsb + OFF_Q;
    const char* kT = (const char*)wsb + OFF_K;
    const char* vT = (const char*)wsb + OFF_VT;
    const char* rT = (const char*)wsb + OFF_R;

    const int tid = threadIdx.x;
    const int w   = tid >> 6;
    const int l   = tid & 63;
    const int lq  = l >> 4;
    const int ln  = l & 15;
    const int rt  = w & 1;
    const int ch  = w >> 1;
    const int lane16 = l * 16;

    ushort_t* wsW = (ushort_t*)(U + w * 1280);           // Ws[w]: [16][40] u16

    const int head = blockIdx.x & 7;                     // bid%8 -> one head per XCD
    const int rest = blockIdx.x >> 3;
    const int p    = rest & 31;
    const int sub  = rest >> 5;                          // 0..3
    const int tileA = 63 - p;
    const int njtA  = (tileA >> 1) + 1;                  // 17..32
    const int tileB = p;

    const int lo = (33 * sub + 3) >> 2;                              // 0,9,17,25
    const int hi = (sub == 3) ? 33 : ((33 * (sub + 1) + 3) >> 2);    // 9,17,25,33

    const char* qh = qT + (size_t)head * 262144;
    const char* kh = kT + (size_t)head * 262144;
    const char* vh = vT + (size_t)head * 262144;

    const int sw = 16 * rt - 32 * ch + 32;   // wave's band-window start (0..48)
    const int stream = head * 32 + p;

    #pragma unroll 1
    for (int seg = 0; seg < 2; ++seg) {
        int tile, jlo, jhi;
        if (seg == 0) { tile = tileA; jlo = lo; jhi = (hi < njtA) ? hi : njtA; }
        else          { tile = tileB; jlo = (lo > njtA ? lo : njtA) - njtA; jhi = hi - njtA; }
        if (jlo >= jhi) continue;            // block-uniform
        const int i0 = tile * 32;

        const char* qp = qh + (size_t)((i0 >> 4) + rt) * 2048 + lane16;
        bf16x8 qf0 = *(const bf16x8*)(qp);
        bf16x8 qf1 = *(const bf16x8*)(qp + 1024);

        // per-segment fragment pointers (advance by fixed strides each iter)
        const char* kp = kh + (size_t)(jlo * 4 + 2 * ch) * 2048 + lane16;
        const char* vp = vh + (size_t)(jlo * 2 + ch) * 4096 + lane16;
        const char* rp = rT + (size_t)(((i0 - jlo * 64 + 1984 + sw) >> 4)) * 2048 + lane16;

        f32x4 acc0 = {0,0,0,0}, acc1 = {0,0,0,0}, acc2 = {0,0,0,0}, acc3 = {0,0,0,0};
        float denv0 = 0.f, denv1 = 0.f, denv2 = 0.f, denv3 = 0.f;

        #pragma unroll 1
        for (int jt = jlo; jt < jhi; ++jt) {
            const int j0 = jt * 64;

            // ---- issue all fragment loads (each = 64 lanes x 16B contiguous)
            bf16x8 b00 = *(const bf16x8*)(kp);
            bf16x8 b01 = *(const bf16x8*)(kp + 1024);
            bf16x8 b10 = *(const bf16x8*)(kp + 2048);
            bf16x8 b11 = *(const bf16x8*)(kp + 3072);
            bf16x8 e0a = *(const bf16x8*)(rp);
            bf16x8 e0b = *(const bf16x8*)(rp + 1024);
            bf16x8 e1a = *(const bf16x8*)(rp + 2048);
            bf16x8 e1b = *(const bf16x8*)(rp + 3072);
            bf16x8 e2a = *(const bf16x8*)(rp + 4096);
            bf16x8 e2b = *(const bf16x8*)(rp + 5120);
            bf16x8 v0  = *(const bf16x8*)(vp);
            bf16x8 v1  = *(const bf16x8*)(vp + 1024);
            bf16x8 v2  = *(const bf16x8*)(vp + 2048);
            bf16x8 v3  = *(const bf16x8*)(vp + 3072);
            kp += 8192; vp += 8192; rp -= 8192;

            // ---- S = Q K^T over wave quadrant
            f32x4 s0 = {0,0,0,0}, s1 = {0,0,0,0};
            s0 = __builtin_amdgcn_mfma_f32_16x16x32_bf16(qf0, b00, s0, 0, 0, 0);
            s0 = __builtin_amdgcn_mfma_f32_16x16x32_bf16(qf1, b01, s0, 0, 0, 0);
            s1 = __builtin_amdgcn_mfma_f32_16x16x32_bf16(qf0, b10, s1, 0, 0, 0);
            s1 = __builtin_amdgcn_mfma_f32_16x16x32_bf16(qf1, b11, s1, 0, 0, 0);

            // ---- T = Q band^T, 3 b-tiles kept in registers (f32, no LDS round-trip)
            f32x4 t0 = {0,0,0,0}, t1 = {0,0,0,0}, t2 = {0,0,0,0};
            t0 = __builtin_amdgcn_mfma_f32_16x16x32_bf16(qf0, e0a, t0, 0, 0, 0);
            t0 = __builtin_amdgcn_mfma_f32_16x16x32_bf16(qf1, e0b, t0, 0, 0, 0);
            t1 = __builtin_amdgcn_mfma_f32_16x16x32_bf16(qf0, e1a, t1, 0, 0, 0);
            t1 = __builtin_amdgcn_mfma_f32_16x16x32_bf16(qf1, e1b, t1, 0, 0, 0);
            t2 = __builtin_amdgcn_mfma_f32_16x16x32_bf16(qf0, e2a, t2, 0, 0, 0);
            t2 = __builtin_amdgcn_mfma_f32_16x16x32_bf16(qf1, e2b, t2, 0, 0, 0);

            // ---- shuffle gather + Taylor weight + mask -> Ws (trunc bf16) + denominator
            // src lane for band value: 16*lq + ((rp2 - ln + 15) & 15); tile select:
            // ct=0 -> (rp2>ln) ? t2 : t1 ; ct=1 -> (rp2>ln) ? t1 : t0
            #pragma unroll
            for (int e = 0; e < 4; ++e) {
                int rp2 = 4 * lq + e;                         // row within strip
                int src = 16 * lq + ((rp2 - ln + 15) & 15);
                float sh0 = __shfl(t0[e], src, 64);
                float sh1 = __shfl(t1[e], src, 64);
                float sh2 = __shfl(t2[e], src, 64);
                bool cond = rp2 > ln;
                float sA = s0[e] + (cond ? sh2 : sh1);        // ct=0, col = ln
                float sB = s1[e] + (cond ? sh1 : sh0);        // ct=1, col = 16+ln
                float wv0 = 1.0f + sA + 0.5f * sA * sA;
                if (j0 + 32 * ch + ln > i0 + 16 * rt + rp2) wv0 = 0.0f;
                union { float f; unsigned u; } u0; u0.f = wv0;
                wsW[rp2 * 40 + ln] = (ushort_t)(u0.u >> 16);         // trunc bf16
                u0.u &= 0xffff0000u;                                 // exact bf16 MFMA sees
                float wv1 = 1.0f + sB + 0.5f * sB * sB;
                if (j0 + 32 * ch + 16 + ln > i0 + 16 * rt + rp2) wv1 = 0.0f;
                union { float f; unsigned u; } u1; u1.f = wv1;
                wsW[rp2 * 40 + 16 + ln] = (ushort_t)(u1.u >> 16);
                u1.u &= 0xffff0000u;
                float de = u0.f + u1.f;
                if (e == 0) denv0 += de; else if (e == 1) denv1 += de;
                else if (e == 2) denv2 += de; else denv3 += de;
            }

            // ---- PV += W * V^T over wave's j-half (K=32)
            {
                bf16x8 af = *(const bf16x8*)&wsW[ln * 40 + 8 * lq];  // wave-private RAW
                acc0 = __builtin_amdgcn_mfma_f32_16x16x32_bf16(af, v0, acc0, 0, 0, 0);
                acc1 = __builtin_amdgcn_mfma_f32_16x16x32_bf16(af, v1, acc1, 0, 0, 0);
                acc2 = __builtin_amdgcn_mfma_f32_16x16x32_bf16(af, v2, acc2, 0, 0, 0);
                acc3 = __builtin_amdgcn_mfma_f32_16x16x32_bf16(af, v3, acc3, 0, 0, 0);
            }
        }

        // ---- reduce denominator across the wave's 16 n-lanes
        #pragma unroll
        for (int off = 1; off <= 8; off <<= 1) {
            denv0 += __shfl_xor(denv0, off);
            denv1 += __shfl_xor(denv1, off);
            denv2 += __shfl_xor(denv2, off);
            denv3 += __shfl_xor(denv3, off);
        }

        // ---- epilogue: combine ch halves in Epi (union with Ws; ordered by barriers)
        __syncthreads();
        if (ch == 0) {
            #pragma unroll
            for (int e = 0; e < 4; ++e) {
                int r = 16 * rt + 4 * lq + e;
                Epi[r * 68 +  0 + ln] = acc0[e];
                Epi[r * 68 + 16 + ln] = acc1[e];
                Epi[r * 68 + 32 + ln] = acc2[e];
                Epi[r * 68 + 48 + ln] = acc3[e];
            }
            if (ln == 0) {
                Epi[(16 * rt + 4 * lq + 0) * 68 + 64] = denv0;
                Epi[(16 * rt + 4 * lq + 1) * 68 + 64] = denv1;
                Epi[(16 * rt + 4 * lq + 2) * 68 + 64] = denv2;
                Epi[(16 * rt + 4 * lq + 3) * 68 + 64] = denv3;
            }
        }
        __syncthreads();
        if (ch == 1) {
            #pragma unroll
            for (int e = 0; e < 4; ++e) {
                int r = 16 * rt + 4 * lq + e;
                Epi[r * 68 +  0 + ln] += acc0[e];
                Epi[r * 68 + 16 + ln] += acc1[e];
                Epi[r * 68 + 32 + ln] += acc2[e];
                Epi[r * 68 + 48 + ln] += acc3[e];
            }
            if (ln == 0) {
                Epi[(16 * rt + 4 * lq + 0) * 68 + 64] += denv0;
                Epi[(16 * rt + 4 * lq + 1) * 68 + 64] += denv1;
                Epi[(16 * rt + 4 * lq + 2) * 68 + 64] += denv2;
                Epi[(16 * rt + 4 * lq + 3) * 68 + 64] += denv3;
            }
        }
        __syncthreads();
        // ---- every segment writes a partial; combine does all division/output
        {
            float* dst = wsPart + ((size_t)((stream * 2 + seg) * 4 + sub)) * (32 * 68);
            for (int idx = tid; idx < 32 * 68; idx += 256) dst[idx] = Epi[idx];
        }
        __syncthreads();   // protect U (Epi) from next segment's Ws writes (loop is barrier-free)
    }
}

// ---------------- combine: sum valid sub-partials per tile, divide, write ----------------
// 512 blocks: one per (stream, tile).
__global__ void combine_kernel(const float* __restrict__ wsPart, float* __restrict__ outg) {
    const int blk  = blockIdx.x >> 1;        // 0..255 = head*32 + p
    const int tsel = blockIdx.x & 1;
    const int head = blk >> 5;
    const int p = blk & 31;
    const int njtA = ((63 - p) >> 1) + 1;
    float* oh = outg + (size_t)head * NN * DD;
    const int tile = tsel ? p : (63 - p);
    const float* base = wsPart + ((size_t)(blk * 2 + tsel)) * 4 * (32 * 68);
    int vmask = 0;
    #pragma unroll
    for (int s = 0; s < 4; ++s) {
        int lo_s = (33 * s + 3) >> 2;
        int hi_s = (s == 3) ? 33 : ((33 * (s + 1) + 3) >> 2);
        bool valid = tsel ? (hi_s > njtA) : (lo_s < njtA);
        if (valid) vmask |= 1 << s;
    }
    #pragma unroll
    for (int e2 = 0; e2 < 8; ++e2) {
        int idx = threadIdx.x + 256 * e2;
        int r = idx >> 6, d = idx & 63;
        float num = 0.f, den = 0.f;
        #pragma unroll
        for (int s = 0; s < 4; ++s) {
            if (vmask & (1 << s)) {
                num += base[s * 2176 + r * 68 + d];
                den += base[s * 2176 + r * 68 + 64];
            }
        }
        oh[(size_t)(tile * 32 + r) * DD + d] = num / den;
    }
}

// ---------------- fallback (round-2 proven kernel, no ws) ----------------
__global__ __launch_bounds__(256, 2)
void fastmax_fallback(const float* __restrict__ qg0, const float* __restrict__ kg0,
                      const float* __restrict__ vg0, const float* __restrict__ rg,
                      float* __restrict__ outg)
{
    __shared__ __align__(16) ushort_t Qs[32][72];
    __shared__ __align__(16) ushort_t Ks2[64][72];
    __shared__ __align__(16) ushort_t Bs2[96][72];
    __shared__ __align__(16) ushort_t Vts2[96][72];
    __shared__ __align__(16) float    Tsf[32][97];
    __shared__ __align__(16) ushort_t Wsf[32][72];
    __shared__ float denomLds[32];

    const int tid = threadIdx.x;
    const int w = tid >> 6, l = tid & 63, lq = l >> 4, ln = l & 15;
    const int head = blockIdx.x & 7, ib = blockIdx.x >> 3;
    const int it = 63 - ib, i0 = it * 32, njt = (it >> 1) + 1;
    const float* qg = qg0 + (size_t)head * NN * DD;
    const float* kg = kg0 + (size_t)head * NN * DD;
    const float* vg = vg0 + (size_t)head * NN * DD;
    float* og = outg + (size_t)head * NN * DD;
    {
        #pragma unroll
        for (int p = 0; p < 2; ++p) {
            int c = tid + 256 * p; int r = c >> 4, dc = (c & 15) << 2;
            float4 f = *(const float4*)&qg[(size_t)(i0 + r) * DD + dc];
            ushort4 u; u.x = f2bf(f.x); u.y = f2bf(f.y); u.z = f2bf(f.z); u.w = f2bf(f.w);
            *(ushort4*)&Qs[r][dc] = u;
        }
        for (int idx = tid; idx < 32 * 72; idx += 256) {
            int rr = idx / 72, cc = idx - rr * 72;
            Vts2[64 + rr][cc] = (rr == 0) ? (ushort_t)0x3F80 : (ushort_t)0;
        }
    }
    f32x4 a0 = {0,0,0,0}, a1 = {0,0,0,0}, a2 = {0,0,0,0};
    const int pr = w & 1, rt = w & 1, cp = w >> 1;
    for (int jt = 0; jt < njt; ++jt) {
        const int j0 = jt * 64;
        __syncthreads();
        #pragma unroll
        for (int p = 0; p < 4; ++p) {
            int c = tid + 256 * p; int r = c >> 4, dc = (c & 15) << 2;
            float4 f = *(const float4*)&kg[(size_t)(j0 + r) * DD + dc];
            ushort4 u; u.x = f2bf(f.x); u.y = f2bf(f.y); u.z = f2bf(f.z); u.w = f2bf(f.w);
            *(ushort4*)&Ks2[r][dc] = u;
        }
        const int relbase = i0 - j0 + 1984;
        #pragma unroll
        for (int p = 0; p < 6; ++p) {
            int c = tid + 256 * p; int r = c >> 4, dc = (c & 15) << 2;
            int row = relbase + r; if (row > 4094) row = 4094;
            float4 f = *(const float4*)&rg[(size_t)row * DD + dc];
            ushort4 u; u.x = f2bf(f.x); u.y = f2bf(f.y); u.z = f2bf(f.z); u.w = f2bf(f.w);
            *(ushort4*)&Bs2[r][dc] = u;
        }
        #pragma unroll
        for (int p = 0; p < 4; ++p) {
            int c = tid + 256 * p; int r = c >> 4, dc = (c & 15) << 2;
            float4 f = *(const float4*)&vg[(size_t)(j0 + r) * DD + dc];
            Vts2[dc + 0][r] = f2bf(f.x); Vts2[dc + 1][r] = f2bf(f.y);
            Vts2[dc + 2][r] = f2bf(f.z); Vts2[dc + 3][r] = f2bf(f.w);
        }
        __syncthreads();
        f32x4 s0 = {0,0,0,0}, s1 = {0,0,0,0};
        #pragma unroll
        for (int ks = 0; ks < 2; ++ks) {
            bf16x8 a = *(const bf16x8*)&Qs[16 * rt + ln][32 * ks + 8 * lq];
            bf16x8 b0 = *(const bf16x8*)&Ks2[32 * cp + ln][32 * ks + 8 * lq];
            bf16x8 b1 = *(const bf16x8*)&Ks2[32 * cp + 16 + ln][32 * ks + 8 * lq];
            s0 = __builtin_amdgcn_mfma_f32_16x16x32_bf16(a, b0, s0, 0, 0, 0);
            s1 = __builtin_amdgcn_mfma_f32_16x16x32_bf16(a, b1, s1, 0, 0, 0);
        }
        #pragma unroll
        for (int kk = 0; kk < 3; ++kk) {
            int bt = (w >> 1) + 2 * kk;
            f32x4 t = {0,0,0,0};
            #pragma unroll
            for (int ks = 0; ks < 2; ++ks) {
                bf16x8 a = *(const bf16x8*)&Qs[16 * rt + ln][32 * ks + 8 * lq];
                bf16x8 b = *(const bf16x8*)&Bs2[16 * bt + ln][32 * ks + 8 * lq];
                t = __builtin_amdgcn_mfma_f32_16x16x32_bf16(a, b, t, 0, 0, 0);
            }
            #pragma unroll
            for (int e = 0; e < 4; ++e) Tsf[16 * rt + 4 * lq + e][16 * bt + ln] = t[e];
        }
        __syncthreads();
        #pragma unroll
        for (int ct2 = 0; ct2 < 2; ++ct2) {
            f32x4 sv = ct2 ? s1 : s0;
            int c_loc = 32 * cp + 16 * ct2 + ln, j = j0 + c_loc;
            #pragma unroll
            for (int e = 0; e < 4; ++e) {
                int r_loc = 16 * rt + 4 * lq + e, i = i0 + r_loc;
                float s = sv[e] + Tsf[r_loc][r_loc - c_loc + 63];
                float wv = 1.0f + s + 0.5f * s * s;
                if (j > i) wv = 0.0f;
                Wsf[r_loc][c_loc] = f2bf(wv);
            }
        }
        __syncthreads();
        {
            bf16x8 af0 = *(const bf16x8*)&Wsf[16 * pr + ln][ 0 + 8 * lq];
            bf16x8 af1 = *(const bf16x8*)&Wsf[16 * pr + ln][32 + 8 * lq];
            int pn0 = w >> 1; bf16x8 b;
            b = *(const bf16x8*)&Vts2[16 * (pn0 + 0) + ln][ 0 + 8 * lq];
            a0 = __builtin_amdgcn_mfma_f32_16x16x32_bf16(af0, b, a0, 0, 0, 0);
            b = *(const bf16x8*)&Vts2[16 * (pn0 + 0) + ln][32 + 8 * lq];
            a0 = __builtin_amdgcn_mfma_f32_16x16x32_bf16(af1, b, a0, 0, 0, 0);
            b = *(const bf16x8*)&Vts2[16 * (pn0 + 2) + ln][ 0 + 8 * lq];
            a1 = __builtin_amdgcn_mfma_f32_16x16x32_bf16(af0, b, a1, 0, 0, 0);
            b = *(const bf16x8*)&Vts2[16 * (pn0 + 2) + ln][32 + 8 * lq];
            a1 = __builtin_amdgcn_mfma_f32_16x16x32_bf16(af1, b, a1, 0, 0, 0);
            b = *(const bf16x8*)&Vts2[16 * (pn0 + 4) + ln][ 0 + 8 * lq];
            a2 = __builtin_amdgcn_mfma_f32_16x16x32_bf16(af0, b, a2, 0, 0, 0);
            b = *(const bf16x8*)&Vts2[16 * (pn0 + 4) + ln][32 + 8 * lq];
            a2 = __builtin_amdgcn_mfma_f32_16x16x32_bf16(af1, b, a2, 0, 0, 0);
        }
    }
    if (w < 2 && ln == 0) {
        #pragma unroll
        for (int e = 0; e < 4; ++e) denomLds[16 * pr + 4 * lq + e] = a2[e];
    }
    __syncthreads();
    #pragma unroll
    for (int k = 0; k < 2; ++k) {
        int pn = (w >> 1) + 2 * k;
        f32x4 acc = k ? a1 : a0;
        #pragma unroll
        for (int e = 0; e < 4; ++e) {
            int r_loc = 16 * pr + 4 * lq + e;
            og[(size_t)(i0 + r_loc) * DD + 16 * pn + ln] = acc[e] / denomLds[r_loc];
        }
    }
}

extern "C" void kernel_launch(void* const* d_in, const int* in_sizes, int n_in,
                              void* d_out, int out_size, void* d_ws, size_t ws_size,
                              hipStream_t stream) {
    const float* q   = (const float*)d_in[0];
    const float* k   = (const float*)d_in[1];
    const float* v   = (const float*)d_in[2];
    const float* rpe = (const float*)d_in[3];
    float* out = (float*)d_out;

    if (ws_size >= WS_NEED) {
        ushort_t* wsb = (ushort_t*)d_ws;
        float* wsPart = (float*)((char*)d_ws + OFF_P);
        hipLaunchKernelGGL(pre_kernel, dim3(832), dim3(256), 0, stream,
                           q, k, rpe, v, wsb);
        hipLaunchKernelGGL(fastmax_main, dim3(1024), dim3(256), 0, stream,
                           wsb, out, wsPart);
        hipLaunchKernelGGL(combine_kernel, dim3(512), dim3(256), 0, stream, wsPart, out);
    } else {
        hipLaunchKernelGGL(fastmax_fallback, dim3(512), dim3(256), 0, stream,
                           q, k, v, rpe, out);
    }
}